// Round 1
// baseline (436.262 us; speedup 1.0000x reference)
//
#include <hip/hip_runtime.h>
#include <hip/hip_bf16.h>

// Problem constants
#define B_    8
#define T_    4096
#define D_    1024
#define S_    64
#define NQ_   8
#define QDIM_ 256
#define TB_   64            // t-rows per partial-sum block
#define NTC_  (T_/TB_)      // 64 chunks
#define NBLK  512           // persistent grid: 2 blocks/CU on 256 CUs

typedef __attribute__((ext_vector_type(4))) unsigned short u16x4;
typedef __attribute__((ext_vector_type(8))) unsigned short u16x8;
typedef __attribute__((ext_vector_type(4))) float f32x4;

__device__ __forceinline__ float b2f(unsigned short u) {
    union { unsigned int i; float f; } v; v.i = ((unsigned int)u) << 16; return v.f;
}
__device__ __forceinline__ unsigned short f2b(float f) {
    __hip_bfloat16 h = __float2bfloat16(f);   // RNE
    return *reinterpret_cast<unsigned short*>(&h);
}

// LDS-tree block reductions, 256 threads, buf is 256-float scratch.
__device__ __forceinline__ float blockSum(float v, float* buf) {
    int tid = threadIdx.x;
    buf[tid] = v; __syncthreads();
    #pragma unroll
    for (int s = 128; s > 0; s >>= 1) { if (tid < s) buf[tid] += buf[tid + s]; __syncthreads(); }
    float r = buf[0]; __syncthreads();
    return r;
}
__device__ __forceinline__ float blockMax(float v, float* buf) {
    int tid = threadIdx.x;
    buf[tid] = v; __syncthreads();
    #pragma unroll
    for (int s = 128; s > 0; s >>= 1) { if (tid < s) buf[tid] = fmaxf(buf[tid], buf[tid + s]); __syncthreads(); }
    float r = buf[0]; __syncthreads();
    return r;
}

// Grid barrier: slot zeroed by hipMemsetAsync before launch; each of the NBLK
// blocks arrives once. Release RMW flushes this XCD's dirty L2 (write-through
// L1 already drained by __syncthreads' vmcnt(0)); relaxed polls add no cache
// maintenance (no L1/L2 thrash for co-resident worker blocks); single acquire
// load on exit invalidates L1/L2 so post-barrier reads see remote writes.
__device__ __forceinline__ void gbar(int* slot) {
    __syncthreads();
    if (threadIdx.x == 0) {
        __hip_atomic_fetch_add(slot, 1, __ATOMIC_RELEASE, __HIP_MEMORY_SCOPE_AGENT);
        while (__hip_atomic_load(slot, __ATOMIC_RELAXED, __HIP_MEMORY_SCOPE_AGENT) < NBLK)
            __builtin_amdgcn_s_sleep(8);
        (void)__hip_atomic_load(slot, __ATOMIC_ACQUIRE, __HIP_MEMORY_SCOPE_AGENT);
    }
    __syncthreads();
}

// Shared-memory union across phases (max = MPS phase, 53.3 KB -> 2 blocks/CU)
struct MpsSh {
    float lcm[6 * 2048];
    float lcf[64];
    float lcl[64];
    float res[8][33];
    float nres[8][33];
    float lm0[64], lm1[64];
    float buf[256];
};
struct LogitsSh { float xs2[256]; float xs[128]; };
struct SmSh     { float qa[QDIM_]; float buf[256]; };
struct AttSh    { float att[S_]; float g[NQ_]; };
union Sh { MpsSh mps; LogitsSh lg; SmSh sm; AttSh att; };

__global__ __launch_bounds__(256, 2)
void k_fused(const void* __restrict__ x,  const void* __restrict__ Wq,
             const void* __restrict__ bq, const void* __restrict__ Wd,
             const void* __restrict__ bd, const void* __restrict__ cf,
             const void* __restrict__ cm, const void* __restrict__ cl,
             float* __restrict__ partials, float* __restrict__ plog,
             float* __restrict__ sm0m, float* __restrict__ sm1m,
             float* __restrict__ feats, float* __restrict__ ovl,
             float* __restrict__ read_proj, float* __restrict__ wdred,
             int* __restrict__ bar, void* __restrict__ out) {
    __shared__ Sh u;
    __shared__ int dcnt[2];
    const int blk = blockIdx.x;
    const int tid = threadIdx.x;

    // ---- Prologue: per-block dtype detection (same 512 B for every block; L2 broadcast)
    bool xf32, wf32;
    {
        if (tid < 2) dcnt[tid] = 0;
        __syncthreads();
        unsigned short ux = ((const unsigned short*)x)[tid];
        unsigned ex = (ux >> 7) & 0xFF;
        bool okx = ((ux & 0x7FFF) == 0) || (ex >= 100 && ex <= 130); // |v| in [2^-27,16)
        unsigned short uw = ((const unsigned short*)Wq)[tid];
        unsigned ew = (uw >> 7) & 0xFF;
        bool okw = ((uw & 0x7FFF) == 0) || (ew >= 96 && ew <= 126);  // |v| in [2^-31,0.5)
        unsigned long long bx = __ballot(okx);
        unsigned long long bw = __ballot(okw);
        if ((tid & 63) == 0) {
            atomicAdd(&dcnt[0], (int)__popcll(bx));
            atomicAdd(&dcnt[1], (int)__popcll(bw));
        }
        __syncthreads();
        xf32 = dcnt[0] < 200;   // 1 => x is f32
        wf32 = dcnt[1] < 200;   // 1 => weights are f32
        __syncthreads();
    }

    // ---- Phase A: partial column sums of x. All 512 blocks: b=blk>>6, tc=blk&63.
    {
        int b  = blk >> 6;
        int tc = blk & 63;
        size_t base = ((size_t)(b * T_ + tc * TB_)) * D_ + tid * 4;
        float a0 = 0.f, a1 = 0.f, a2 = 0.f, a3 = 0.f;
        if (xf32) {
            const float* px = (const float*)x + base;
            #pragma unroll 8
            for (int i = 0; i < TB_; ++i) {
                f32x4 v = *reinterpret_cast<const f32x4*>(px + (size_t)i * D_);
                a0 += v[0]; a1 += v[1]; a2 += v[2]; a3 += v[3];
            }
        } else {
            const unsigned short* px = (const unsigned short*)x + base;
            #pragma unroll 8
            for (int i = 0; i < TB_; ++i) {
                u16x4 v = *reinterpret_cast<const u16x4*>(px + (size_t)i * D_);
                a0 += b2f(v[0]); a1 += b2f(v[1]); a2 += b2f(v[2]); a3 += b2f(v[3]);
            }
        }
        float* dst = partials + ((size_t)(tc * B_ + b)) * D_ + tid * 4;
        f32x4 r; r[0] = a0; r[1] = a1; r[2] = a2; r[3] = a3;
        *reinterpret_cast<f32x4*>(dst) = r;
    }
    gbar(bar + 0);

    // ---- Phase B: blocks 0-63 partial logits; blocks 64-95 reduce Wd -> wdred[8][1024].
    if (blk < 64) {
        int b = blk >> 3, dc = blk & 7;
        int d0 = dc * 128;
        // 2-way parallel reduction over tc (all 256 threads)
        float a = 0.f;
        for (int tc = (tid >> 7); tc < NTC_; tc += 2)
            a += partials[((size_t)(tc * B_ + b)) * D_ + d0 + (tid & 127)];
        u.lg.xs2[tid] = a;
        __syncthreads();
        if (tid < 128) u.lg.xs[tid] = (u.lg.xs2[tid] + u.lg.xs2[tid + 128]) * (1.f / (float)T_);
        __syncthreads();
        float lg = 0.f;
        if (wf32) {
            const float* w = (const float*)Wq + (size_t)d0 * QDIM_ + tid;
            #pragma unroll 8
            for (int d = 0; d < 128; ++d) lg += u.lg.xs[d] * w[(size_t)d * QDIM_];
        } else {
            const unsigned short* w = (const unsigned short*)Wq + (size_t)d0 * QDIM_ + tid;
            #pragma unroll 8
            for (int d = 0; d < 128; ++d) lg += u.lg.xs[d] * b2f(w[(size_t)d * QDIM_]);
        }
        plog[((size_t)(b * 8 + dc)) * QDIM_ + tid] = lg;
    } else if (blk < 96) {
        // wdred[j][d] = sum_{k<32} Wd[j+8k][d]  (slot_values tiling collapses Wd)
        int bi = blk - 64;
        int j = tid >> 5;
        int d = bi * 32 + (tid & 31);
        float a = 0.f;
        if (wf32) {
            const float* w = (const float*)Wd;
            #pragma unroll 8
            for (int k = 0; k < 32; ++k) a += w[(size_t)(j + 8 * k) * D_ + d];
        } else {
            const unsigned short* w = (const unsigned short*)Wd;
            #pragma unroll 8
            for (int k = 0; k < 32; ++k) a += b2f(w[(size_t)(j + 8 * k) * D_ + d]);
        }
        wdred[(size_t)j * D_ + d] = a;
    }
    gbar(bar + 1);

    // ---- Phase C: blocks 0-7: combine logits + bq, softmax, clamped amp-means.
    if (blk < 8) {
        int b = blk;
        float lg = wf32 ? ((const float*)bq)[tid] : b2f(((const unsigned short*)bq)[tid]);
        for (int dc = 0; dc < 8; ++dc) lg += plog[((size_t)(b * 8 + dc)) * QDIM_ + tid];
        float mx = blockMax(lg, u.sm.buf);
        float e = __expf(lg - mx);
        float ss = blockSum(e, u.sm.buf);
        u.sm.qa[tid] = e / ss;
        __syncthreads();
        if (tid < 16) {
            int q = tid >> 1, bit = tid & 1;
            int sw = 1 << (7 - q);
            float acc = 0.f;
            for (int i = 0; i < sw; ++i) {
                int idx = 2 * sw * i + bit * sw;
                if (idx > QDIM_ - 1) idx = QDIM_ - 1;
                acc += u.sm.qa[idx];
            }
            float m = acc / (float)sw;
            if (bit == 0) sm0m[b * 8 + q] = m; else sm1m[b * 8 + q] = m;
        }
    }
    gbar(bar + 2);

    // ---- Phase D: blocks 0-63: MPS contraction + feats (one block per slot).
    if (blk < S_) {
        int s = blk;
        MpsSh& M = u.mps;
        if (wf32) {
            const float* pcm = (const float*)cm + (size_t)s * 12288;
            for (int i = tid; i < 12288; i += 256) M.lcm[i] = pcm[i];
            if (tid < 64) {
                M.lcf[tid] = ((const float*)cf)[s * 64 + tid];
                M.lcl[tid] = ((const float*)cl)[s * 64 + tid];
            }
        } else {
            const unsigned short* pcm = (const unsigned short*)cm + (size_t)s * 12288;
            for (int i = tid; i < 12288; i += 256) M.lcm[i] = b2f(pcm[i]);
            if (tid < 64) {
                M.lcf[tid] = b2f(((const unsigned short*)cf)[s * 64 + tid]);
                M.lcl[tid] = b2f(((const unsigned short*)cl)[s * 64 + tid]);
            }
        }
        if (tid < 64) { M.lm0[tid] = sm0m[tid]; M.lm1[tid] = sm1m[tid]; }
        __syncthreads();

        // feats from LDS
        {
            float v = (tid < 64) ? M.lcf[tid] : 0.f;
            float f0 = blockSum(v, M.buf) * (1.f / 64.f);
            float fj[6];
            for (int j = 0; j < 6; ++j) {
                float a = 0.f;
                for (int k = tid; k < 2048; k += 256) a += M.lcm[j * 2048 + k];
                fj[j] = blockSum(a, M.buf) * (1.f / 2048.f);
            }
            float w = (tid < 64) ? M.lcl[tid] : 0.f;
            float fl = blockSum(w, M.buf) * (1.f / 64.f);
            if (tid == 0) {
                feats[s * 8 + 0] = f0;
                #pragma unroll
                for (int j = 0; j < 6; ++j) feats[s * 8 + 1 + j] = fj[j];
                feats[s * 8 + 7] = fl;
            }
        }

        int b = tid >> 5, r = tid & 31;
        M.res[b][r] = M.lm0[b * 8 + 0] * M.lcf[r] + M.lm1[b * 8 + 0] * M.lcf[32 + r];
        __syncthreads();
        for (int q = 1; q <= 6; ++q) {
            float m0 = M.lm0[b * 8 + q], m1 = M.lm1[b * 8 + q];
            const float* C = &M.lcm[(q - 1) * 2048];
            float acc = 0.f;
            #pragma unroll 8
            for (int l = 0; l < 32; ++l)
                acc += M.res[b][l] * (m0 * C[l * 64 + r] + m1 * C[l * 64 + 32 + r]);
            M.nres[b][r] = acc;
            __syncthreads();
            M.res[b][r] = M.nres[b][r];
            __syncthreads();
        }
        {
            float m0 = M.lm0[b * 8 + 7], m1 = M.lm1[b * 8 + 7];
            float p = M.res[b][r] * (m0 * M.lcl[r * 2] + m1 * M.lcl[r * 2 + 1]);
            #pragma unroll
            for (int off = 16; off > 0; off >>= 1) p += __shfl_xor(p, off, 64);
            if (r == 0) ovl[b * 64 + s] = p;
        }
    }
    gbar(bar + 3);

    // ---- Phase E: blocks 0-7: attention softmax + g + read_proj via wdred.
    if (blk < 8) {
        int b = blk;
        if (tid < 64) {
            float o = ovl[b * 64 + tid];
            float mx = o;
            #pragma unroll
            for (int off = 32; off > 0; off >>= 1) mx = fmaxf(mx, __shfl_xor(mx, off, 64));
            float e = __expf(o - mx);
            float se = e;
            #pragma unroll
            for (int off = 32; off > 0; off >>= 1) se += __shfl_xor(se, off, 64);
            u.att.att[tid] = e / se;
        }
        __syncthreads();
        if (tid < 8) {
            float g = 0.f;
            for (int s2 = 0; s2 < S_; ++s2) g += u.att.att[s2] * feats[s2 * 8 + tid];
            u.att.g[tid] = g;
        }
        __syncthreads();
        #pragma unroll
        for (int i = 0; i < 4; ++i) {
            int d = tid + i * 256;
            float a = wf32 ? ((const float*)bd)[d] : b2f(((const unsigned short*)bd)[d]);
            #pragma unroll
            for (int j = 0; j < 8; ++j) a += u.att.g[j] * wdred[(size_t)j * D_ + d];
            read_proj[(size_t)b * D_ + d] = a;
        }
    }
    gbar(bar + 4);

    // ---- Phase F: out = x + read_proj broadcast; grid-stride, 8 elems/thread.
    {
        for (int it = 0; it < 32; ++it) {
            size_t base = (((size_t)(it * NBLK + blk)) * 256 + tid) * 8;
            int b = (int)(base >> 22);          // T_*D_ = 2^22
            int d = (int)(base & (D_ - 1));
            const float* r = read_proj + (size_t)b * D_ + d;
            f32x4 r0 = *reinterpret_cast<const f32x4*>(r);
            f32x4 r1 = *reinterpret_cast<const f32x4*>(r + 4);
            if (xf32) {
                const float* px = (const float*)x + base;
                f32x4 v0 = *reinterpret_cast<const f32x4*>(px);
                f32x4 v1 = *reinterpret_cast<const f32x4*>(px + 4);
                f32x4 o0 = v0 + r0;
                f32x4 o1 = v1 + r1;
                float* po = (float*)out + base;
                *reinterpret_cast<f32x4*>(po) = o0;
                *reinterpret_cast<f32x4*>(po + 4) = o1;
            } else {
                u16x8 v = *reinterpret_cast<const u16x8*>((const unsigned short*)x + base);
                u16x8 o;
                #pragma unroll
                for (int k = 0; k < 4; ++k) o[k] = f2b(b2f(v[k]) + r0[k]);
                #pragma unroll
                for (int k = 0; k < 4; ++k) o[4 + k] = f2b(b2f(v[4 + k]) + r1[k]);
                *reinterpret_cast<u16x8*>((unsigned short*)out + base) = o;
            }
        }
    }
}

extern "C" void kernel_launch(void* const* d_in, const int* in_sizes, int n_in,
                              void* d_out, int out_size, void* d_ws, size_t ws_size,
                              hipStream_t stream) {
    const void* x  = d_in[0];
    const void* Wq = d_in[1];
    const void* bq = d_in[2];
    const void* Wd = d_in[3];
    const void* bd = d_in[4];
    const void* cf = d_in[5];
    const void* cm = d_in[6];
    const void* cl = d_in[7];

    float* ws        = (float*)d_ws;
    float* partials  = ws;                        // 524288 f32 (2 MB)
    float* plog      = partials + 524288;         // 16384
    float* sm0m      = plog + 16384;              // 64
    float* sm1m      = sm0m + 64;                 // 64
    float* feats     = sm1m + 64;                 // 512
    float* ovl       = feats + 512;               // 512
    float* read_proj = ovl + 512;                 // 8192
    float* wdred     = read_proj + 8192;          // 8192
    int*   bar       = (int*)(wdred + 8192);      // 8 ints (5 used)

    hipMemsetAsync(bar, 0, 32, stream);
    k_fused<<<NBLK, 256, 0, stream>>>(x, Wq, bq, Wd, bd, cf, cm, cl,
                                      partials, plog, sm0m, sm1m, feats, ovl,
                                      read_proj, wdred, bar, d_out);
}

// Round 2
// 314.565 us; speedup vs baseline: 1.3869x; 1.3869x over previous
//
#include <hip/hip_runtime.h>
#include <hip/hip_bf16.h>

// Problem constants
#define B_    8
#define T_    4096
#define D_    1024
#define S_    64
#define NQ_   8
#define QDIM_ 256
#define TB_   64            // t-rows per partial-sum block
#define NTC_  (T_/TB_)      // 64 chunks
#define NMID  64            // blocks in the fused middle kernel (all co-resident: 64 < 256 CUs)

typedef __attribute__((ext_vector_type(4))) unsigned short u16x4;
typedef __attribute__((ext_vector_type(8))) unsigned short u16x8;
typedef __attribute__((ext_vector_type(4))) float f32x4;

__device__ __forceinline__ float b2f(unsigned short u) {
    union { unsigned int i; float f; } v; v.i = ((unsigned int)u) << 16; return v.f;
}
__device__ __forceinline__ unsigned short f2b(float f) {
    __hip_bfloat16 h = __float2bfloat16(f);   // RNE
    return *reinterpret_cast<unsigned short*>(&h);
}

// LDS-tree block reductions, 256 threads, buf is 256-float scratch.
__device__ __forceinline__ float blockSum(float v, float* buf) {
    int tid = threadIdx.x;
    buf[tid] = v; __syncthreads();
    #pragma unroll
    for (int s = 128; s > 0; s >>= 1) { if (tid < s) buf[tid] += buf[tid + s]; __syncthreads(); }
    float r = buf[0]; __syncthreads();
    return r;
}
__device__ __forceinline__ float blockMax(float v, float* buf) {
    int tid = threadIdx.x;
    buf[tid] = v; __syncthreads();
    #pragma unroll
    for (int s = 128; s > 0; s >>= 1) { if (tid < s) buf[tid] = fmaxf(buf[tid], buf[tid + s]); __syncthreads(); }
    float r = buf[0]; __syncthreads();
    return r;
}

// Per-block dtype detection: 256 threads sample 256 u16 words (same 512 B for
// every block -> L2 broadcast). bf16 buffers decode ~256/256 plausible; the
// lo-halves of f32 words have random exponent bits -> ~143/256.
__device__ __forceinline__ bool detect_f32(const unsigned short* __restrict__ p,
                                           unsigned elo, unsigned ehi, int* cnt) {
    int tid = threadIdx.x;
    if (tid == 0) *cnt = 0;
    __syncthreads();
    unsigned short u = p[tid];
    unsigned e = (u >> 7) & 0xFF;
    bool ok = ((u & 0x7FFF) == 0) || (e >= elo && e <= ehi);
    unsigned long long bm = __ballot(ok);
    if ((tid & 63) == 0) atomicAdd(cnt, (int)__popcll(bm));
    __syncthreads();
    bool isf32 = (*cnt < 200);
    __syncthreads();
    return isf32;
}

// Grid barrier among NMID co-resident blocks. Slots zeroed by hipMemsetAsync
// each launch. Far cheaper than the 512-block variant: 64 release-flush /
// acquire-inv pairs per barrier instead of 512.
__device__ __forceinline__ void gbar(int* slot, int target) {
    __syncthreads();
    if (threadIdx.x == 0) {
        __hip_atomic_fetch_add(slot, 1, __ATOMIC_RELEASE, __HIP_MEMORY_SCOPE_AGENT);
        while (__hip_atomic_load(slot, __ATOMIC_RELAXED, __HIP_MEMORY_SCOPE_AGENT) < target)
            __builtin_amdgcn_s_sleep(4);
        (void)__hip_atomic_load(slot, __ATOMIC_ACQUIRE, __HIP_MEMORY_SCOPE_AGENT);
    }
    __syncthreads();
}

// K1: partial column sums of x. partials[tc][b][d] f32. grid = 512, 256 thr.
// No grid barrier, tiny LDS -> full streaming occupancy.
__global__ __launch_bounds__(256)
void k_colsum(const void* __restrict__ x, float* __restrict__ partials) {
    __shared__ int cnt;
    bool xf32 = detect_f32((const unsigned short*)x, 100, 130, &cnt); // |v| in [2^-27,16)
    int blk = blockIdx.x;
    int b  = blk >> 6;
    int tc = blk & 63;
    int tid = threadIdx.x;
    size_t base = ((size_t)(b * T_ + tc * TB_)) * D_ + tid * 4;
    float a0 = 0.f, a1 = 0.f, a2 = 0.f, a3 = 0.f;
    if (xf32) {
        const float* px = (const float*)x + base;
        #pragma unroll 8
        for (int i = 0; i < TB_; ++i) {
            f32x4 v = *reinterpret_cast<const f32x4*>(px + (size_t)i * D_);
            a0 += v[0]; a1 += v[1]; a2 += v[2]; a3 += v[3];
        }
    } else {
        const unsigned short* px = (const unsigned short*)x + base;
        #pragma unroll 8
        for (int i = 0; i < TB_; ++i) {
            u16x4 v = *reinterpret_cast<const u16x4*>(px + (size_t)i * D_);
            a0 += b2f(v[0]); a1 += b2f(v[1]); a2 += b2f(v[2]); a3 += b2f(v[3]);
        }
    }
    float* dst = partials + ((size_t)(tc * B_ + b)) * D_ + tid * 4;
    f32x4 r; r[0] = a0; r[1] = a1; r[2] = a2; r[3] = a3;
    *reinterpret_cast<f32x4*>(dst) = r;
}

// Shared-memory union across k_mid phases (max = MPS phase, ~53 KB; grid=64
// blocks so occupancy is irrelevant here).
struct MpsSh {
    float lcm[6 * 2048];
    float lcf[64];
    float lcl[64];
    float res[8][33];
    float nres[8][33];
    float lm0[64], lm1[64];
    float buf[256];
};
struct LogitsSh { float xs2[256]; float xs[128]; };
struct SmSh     { float qa[QDIM_]; float buf[256]; };
struct AttSh    { float att[S_]; float g[NQ_]; };
union Sh { MpsSh mps; LogitsSh lg; SmSh sm; AttSh att; };

// K2: fused middle chain. grid = 64 blocks, 3 grid barriers.
//   Phase B: blocks 0-63: finish xs, partial logits; each block also reduces a
//            128-wide slice of Wd -> wdred[8][1024].
//   Phase C: blocks 0-7: combine logits + bq, softmax, clamped amp-means.
//   Phase D: blocks 0-63: MPS contraction + feats (one block per slot).
//   Phase E: blocks 0-7: attention softmax + g + read_proj via wdred.
__global__ __launch_bounds__(256)
void k_mid(const void* __restrict__ Wq, const void* __restrict__ bq,
           const void* __restrict__ Wd, const void* __restrict__ bd,
           const void* __restrict__ cf, const void* __restrict__ cm,
           const void* __restrict__ cl,
           const float* __restrict__ partials, float* __restrict__ plog,
           float* __restrict__ sm0m, float* __restrict__ sm1m,
           float* __restrict__ feats, float* __restrict__ ovl,
           float* __restrict__ read_proj, float* __restrict__ wdred,
           int* __restrict__ bar) {
    __shared__ Sh u;
    __shared__ int cnt;
    const int blk = blockIdx.x;
    const int tid = threadIdx.x;
    bool wf32 = detect_f32((const unsigned short*)Wq, 96, 126, &cnt); // |v| in [2^-31,0.5)

    // ---- Phase B
    {
        int b = blk >> 3, dc = blk & 7;
        int d0 = dc * 128;
        float a = 0.f;
        for (int tc = (tid >> 7); tc < NTC_; tc += 2)
            a += partials[((size_t)(tc * B_ + b)) * D_ + d0 + (tid & 127)];
        u.lg.xs2[tid] = a;
        __syncthreads();
        if (tid < 128) u.lg.xs[tid] = (u.lg.xs2[tid] + u.lg.xs2[tid + 128]) * (1.f / (float)T_);
        __syncthreads();
        float lg = 0.f;
        if (wf32) {
            const float* w = (const float*)Wq + (size_t)d0 * QDIM_ + tid;
            #pragma unroll 8
            for (int d = 0; d < 128; ++d) lg += u.lg.xs[d] * w[(size_t)d * QDIM_];
        } else {
            const unsigned short* w = (const unsigned short*)Wq + (size_t)d0 * QDIM_ + tid;
            #pragma unroll 8
            for (int d = 0; d < 128; ++d) lg += u.lg.xs[d] * b2f(w[(size_t)d * QDIM_]);
        }
        plog[((size_t)(b * 8 + dc)) * QDIM_ + tid] = lg;
        // wdred slice: flat index [blk*128, blk*128+128)
        if (tid < 128) {
            int flat = blk * 128 + tid;
            int j = flat >> 10, d = flat & (D_ - 1);
            float s = 0.f;
            if (wf32) {
                const float* w = (const float*)Wd;
                #pragma unroll 8
                for (int k = 0; k < 32; ++k) s += w[(size_t)(j + 8 * k) * D_ + d];
            } else {
                const unsigned short* w = (const unsigned short*)Wd;
                #pragma unroll 8
                for (int k = 0; k < 32; ++k) s += b2f(w[(size_t)(j + 8 * k) * D_ + d]);
            }
            wdred[flat] = s;
        }
    }
    gbar(bar + 0, NMID);

    // ---- Phase C
    if (blk < 8) {
        int b = blk;
        float lg = wf32 ? ((const float*)bq)[tid] : b2f(((const unsigned short*)bq)[tid]);
        for (int dc = 0; dc < 8; ++dc) lg += plog[((size_t)(b * 8 + dc)) * QDIM_ + tid];
        float mx = blockMax(lg, u.sm.buf);
        float e = __expf(lg - mx);
        float ss = blockSum(e, u.sm.buf);
        u.sm.qa[tid] = e / ss;
        __syncthreads();
        if (tid < 16) {
            int q = tid >> 1, bit = tid & 1;
            int sw = 1 << (7 - q);
            float acc = 0.f;
            for (int i = 0; i < sw; ++i) {
                int idx = 2 * sw * i + bit * sw;
                if (idx > QDIM_ - 1) idx = QDIM_ - 1;
                acc += u.sm.qa[idx];
            }
            float m = acc / (float)sw;
            if (bit == 0) sm0m[b * 8 + q] = m; else sm1m[b * 8 + q] = m;
        }
    }
    gbar(bar + 1, NMID);

    // ---- Phase D: one block per slot
    {
        int s = blk;
        MpsSh& M = u.mps;
        if (wf32) {
            const float* pcm = (const float*)cm + (size_t)s * 12288;
            for (int i = tid; i < 12288; i += 256) M.lcm[i] = pcm[i];
            if (tid < 64) {
                M.lcf[tid] = ((const float*)cf)[s * 64 + tid];
                M.lcl[tid] = ((const float*)cl)[s * 64 + tid];
            }
        } else {
            const unsigned short* pcm = (const unsigned short*)cm + (size_t)s * 12288;
            for (int i = tid; i < 12288; i += 256) M.lcm[i] = b2f(pcm[i]);
            if (tid < 64) {
                M.lcf[tid] = b2f(((const unsigned short*)cf)[s * 64 + tid]);
                M.lcl[tid] = b2f(((const unsigned short*)cl)[s * 64 + tid]);
            }
        }
        if (tid < 64) { M.lm0[tid] = sm0m[tid]; M.lm1[tid] = sm1m[tid]; }
        __syncthreads();

        // feats from LDS
        {
            float v = (tid < 64) ? M.lcf[tid] : 0.f;
            float f0 = blockSum(v, M.buf) * (1.f / 64.f);
            float fj[6];
            for (int j = 0; j < 6; ++j) {
                float a = 0.f;
                for (int k = tid; k < 2048; k += 256) a += M.lcm[j * 2048 + k];
                fj[j] = blockSum(a, M.buf) * (1.f / 2048.f);
            }
            float w = (tid < 64) ? M.lcl[tid] : 0.f;
            float fl = blockSum(w, M.buf) * (1.f / 64.f);
            if (tid == 0) {
                feats[s * 8 + 0] = f0;
                #pragma unroll
                for (int j = 0; j < 6; ++j) feats[s * 8 + 1 + j] = fj[j];
                feats[s * 8 + 7] = fl;
            }
        }

        int b = tid >> 5, r = tid & 31;
        M.res[b][r] = M.lm0[b * 8 + 0] * M.lcf[r] + M.lm1[b * 8 + 0] * M.lcf[32 + r];
        __syncthreads();
        for (int q = 1; q <= 6; ++q) {
            float m0 = M.lm0[b * 8 + q], m1 = M.lm1[b * 8 + q];
            const float* C = &M.lcm[(q - 1) * 2048];
            float acc = 0.f;
            #pragma unroll 8
            for (int l = 0; l < 32; ++l)
                acc += M.res[b][l] * (m0 * C[l * 64 + r] + m1 * C[l * 64 + 32 + r]);
            M.nres[b][r] = acc;
            __syncthreads();
            M.res[b][r] = M.nres[b][r];
            __syncthreads();
        }
        {
            float m0 = M.lm0[b * 8 + 7], m1 = M.lm1[b * 8 + 7];
            float p = M.res[b][r] * (m0 * M.lcl[r * 2] + m1 * M.lcl[r * 2 + 1]);
            #pragma unroll
            for (int off = 16; off > 0; off >>= 1) p += __shfl_xor(p, off, 64);
            if (r == 0) ovl[b * 64 + s] = p;
        }
    }
    gbar(bar + 2, NMID);

    // ---- Phase E
    if (blk < 8) {
        int b = blk;
        if (tid < 64) {
            float o = ovl[b * 64 + tid];
            float mx = o;
            #pragma unroll
            for (int off = 32; off > 0; off >>= 1) mx = fmaxf(mx, __shfl_xor(mx, off, 64));
            float e = __expf(o - mx);
            float se = e;
            #pragma unroll
            for (int off = 32; off > 0; off >>= 1) se += __shfl_xor(se, off, 64);
            u.att.att[tid] = e / se;
        }
        __syncthreads();
        if (tid < 8) {
            float g = 0.f;
            for (int s2 = 0; s2 < S_; ++s2) g += u.att.att[s2] * feats[s2 * 8 + tid];
            u.att.g[tid] = g;
        }
        __syncthreads();
        #pragma unroll
        for (int i = 0; i < 4; ++i) {
            int d = tid + i * 256;
            float a = wf32 ? ((const float*)bd)[d] : b2f(((const unsigned short*)bd)[d]);
            #pragma unroll
            for (int j = 0; j < 8; ++j) a += u.att.g[j] * wdred[(size_t)j * D_ + d];
            read_proj[(size_t)b * D_ + d] = a;
        }
    }
}

// K3: out = x + read_proj[b,:] broadcast. grid = 16384 -> high occupancy
// streaming. Output dtype follows x's dtype.
__global__ __launch_bounds__(256)
void k_add(const void* __restrict__ x, const float* __restrict__ rp,
           void* __restrict__ out) {
    __shared__ int cnt;
    bool xf32 = detect_f32((const unsigned short*)x, 100, 130, &cnt);
    size_t base = (((size_t)blockIdx.x) * 256 + threadIdx.x) * 8;
    int b = (int)(base >> 22);          // T_*D_ = 2^22
    int d = (int)(base & (D_ - 1));
    const float* r = rp + (size_t)b * D_ + d;
    f32x4 r0 = *reinterpret_cast<const f32x4*>(r);
    f32x4 r1 = *reinterpret_cast<const f32x4*>(r + 4);
    if (xf32) {
        const float* px = (const float*)x + base;
        f32x4 v0 = *reinterpret_cast<const f32x4*>(px);
        f32x4 v1 = *reinterpret_cast<const f32x4*>(px + 4);
        f32x4 o0 = v0 + r0;
        f32x4 o1 = v1 + r1;
        float* po = (float*)out + base;
        *reinterpret_cast<f32x4*>(po) = o0;
        *reinterpret_cast<f32x4*>(po + 4) = o1;
    } else {
        u16x8 v = *reinterpret_cast<const u16x8*>((const unsigned short*)x + base);
        u16x8 o;
        #pragma unroll
        for (int k = 0; k < 4; ++k) o[k] = f2b(b2f(v[k]) + r0[k]);
        #pragma unroll
        for (int k = 0; k < 4; ++k) o[4 + k] = f2b(b2f(v[4 + k]) + r1[k]);
        *reinterpret_cast<u16x8*>((unsigned short*)out + base) = o;
    }
}

extern "C" void kernel_launch(void* const* d_in, const int* in_sizes, int n_in,
                              void* d_out, int out_size, void* d_ws, size_t ws_size,
                              hipStream_t stream) {
    const void* x  = d_in[0];
    const void* Wq = d_in[1];
    const void* bq = d_in[2];
    const void* Wd = d_in[3];
    const void* bd = d_in[4];
    const void* cf = d_in[5];
    const void* cm = d_in[6];
    const void* cl = d_in[7];

    float* ws        = (float*)d_ws;
    float* partials  = ws;                        // 524288 f32 (2 MB)
    float* plog      = partials + 524288;         // 16384
    float* sm0m      = plog + 16384;              // 64
    float* sm1m      = sm0m + 64;                 // 64
    float* feats     = sm1m + 64;                 // 512
    float* ovl       = feats + 512;               // 512
    float* read_proj = ovl + 512;                 // 8192
    float* wdred     = read_proj + 8192;          // 8192
    int*   bar       = (int*)(wdred + 8192);      // 8 ints (3 used)

    hipMemsetAsync(bar, 0, 32, stream);
    k_colsum<<<B_ * NTC_, 256, 0, stream>>>(x, partials);
    k_mid<<<NMID, 256, 0, stream>>>(Wq, bq, Wd, bd, cf, cm, cl,
                                    partials, plog, sm0m, sm1m, feats, ovl,
                                    read_proj, wdred, bar);
    k_add<<<(B_ * T_ * D_) / 2048, 256, 0, stream>>>(x, read_proj, d_out);
}